// Round 2
// baseline (1637.663 us; speedup 1.0000x reference)
//
#include <hip/hip_runtime.h>
#include <hip/hip_bf16.h>

// MarkowitzPortfolioOptimizer: MLP -> mu, p = -gamma*mu; 200 FISTA iters of
// simplex-projected QP per batch row. B=16384, D=128, H1=32, H2=16, N=64.
//
// Dtypes: ALL float32 per the reference (round-1 post-mortem: bf16 read of
// f32 sigma produced inf-garbage -> NaN in power iteration).

#define B_ROWS 16384
#define NA 64
#define N_FISTA 200
#define N_POWER 256

__device__ __forceinline__ float rdlane(float v, int l) {
  return __int_as_float(__builtin_amdgcn_readlane(__float_as_int(v), l));
}

// sum across 64 lanes (all lanes get result)
__device__ __forceinline__ float wave_sum64(float x) {
#pragma unroll
  for (int m = 32; m >= 1; m >>= 1) x += __shfl_xor(x, m, 64);
  return x;
}

// grad_lane = sum_i sig[i] * y_i, sig[] = column `lane` of sigma (64 VGPRs)
__device__ __forceinline__ float matvec64(const float* sig, float y) {
  float g0 = 0.f, g1 = 0.f, g2 = 0.f, g3 = 0.f;
#pragma unroll
  for (int i = 0; i < 64; i += 4) {
    g0 = fmaf(sig[i + 0], rdlane(y, i + 0), g0);
    g1 = fmaf(sig[i + 1], rdlane(y, i + 1), g1);
    g2 = fmaf(sig[i + 2], rdlane(y, i + 2), g2);
    g3 = fmaf(sig[i + 3], rdlane(y, i + 3), g3);
  }
  return (g0 + g1) + (g2 + g3);
}

// ---------------------------------------------------------------------------
// Kernel 1: blocks 0..63: MLP (one thread per row). block 64: power iteration
// for L = lambda_max(sigma); writes step = 1/L. p = -gamma*mu in f32 ws.
// ---------------------------------------------------------------------------
__global__ void mlp_power_kernel(const float* __restrict__ x,
                                 const float* __restrict__ W1, const float* __restrict__ b1,
                                 const float* __restrict__ W2, const float* __restrict__ b2,
                                 const float* __restrict__ W3, const float* __restrict__ b3,
                                 const float* __restrict__ sigma,
                                 const float* __restrict__ gamma,
                                 float* __restrict__ mu_out,  // d_out + B*NA
                                 float* __restrict__ p_out,   // ws
                                 float* __restrict__ step_out) {
  if (blockIdx.x == 64) {
    // ---- power iteration, one wave ----
    int tid = threadIdx.x;
    if (tid < 64) {
      int lane = tid;
      float sig[64];
#pragma unroll
      for (int i = 0; i < 64; ++i) sig[i] = sigma[i * 64 + lane];
      float v = 0.125f;
      for (int it = 0; it < N_POWER; ++it) {
        float u = matvec64(sig, v);
        float n2 = wave_sum64(u * u);
        v = u * rsqrtf(n2);
      }
      float u = matvec64(sig, v);
      float num = wave_sum64(v * u);  // v^T Sigma v
      float den = wave_sum64(v * v);  // ||v||^2 (=1)
      if (lane == 0) step_out[0] = den / num;  // 1/L
    }
    return;
  }

  // ---- MLP ----
  __shared__ float sW1[128 * 32], sW2[32 * 16], sW3[16 * 64];
  __shared__ float sb1[32], sb2[16], sb3[64];
  int tid = threadIdx.x;
  for (int i = tid; i < 128 * 32; i += 256) sW1[i] = W1[i];
  for (int i = tid; i < 32 * 16; i += 256) sW2[i] = W2[i];
  for (int i = tid; i < 16 * 64; i += 256) sW3[i] = W3[i];
  if (tid < 32) sb1[tid] = b1[tid];
  if (tid < 16) sb2[tid] = b2[tid];
  if (tid < 64) sb3[tid] = b3[tid];
  __syncthreads();

  int row = blockIdx.x * 256 + tid;
  float gamma_f = gamma[0];

  float h1[32];
#pragma unroll
  for (int j = 0; j < 32; ++j) h1[j] = sb1[j];
  for (int k = 0; k < 128; k += 4) {
    float4 xk = *(const float4*)&x[row * 128 + k];
#pragma unroll
    for (int j = 0; j < 32; ++j) {
      h1[j] = fmaf(xk.x, sW1[(k + 0) * 32 + j], h1[j]);
      h1[j] = fmaf(xk.y, sW1[(k + 1) * 32 + j], h1[j]);
      h1[j] = fmaf(xk.z, sW1[(k + 2) * 32 + j], h1[j]);
      h1[j] = fmaf(xk.w, sW1[(k + 3) * 32 + j], h1[j]);
    }
  }
#pragma unroll
  for (int j = 0; j < 32; ++j) h1[j] = fmaxf(h1[j], 0.0f);

  float h2[16];
#pragma unroll
  for (int j = 0; j < 16; ++j) h2[j] = sb2[j];
#pragma unroll
  for (int k = 0; k < 32; ++k) {
#pragma unroll
    for (int j = 0; j < 16; ++j) h2[j] = fmaf(h1[k], sW2[k * 16 + j], h2[j]);
  }
#pragma unroll
  for (int j = 0; j < 16; ++j) h2[j] = fmaxf(h2[j], 0.0f);

  for (int o = 0; o < 64; ++o) {
    float mu = sb3[o];
#pragma unroll
    for (int k = 0; k < 16; ++k) mu = fmaf(h2[k], sW3[k * 64 + o], mu);
    mu_out[row * 64 + o] = mu;
    p_out[row * 64 + o] = -gamma_f * mu;
  }
}

// ---------------------------------------------------------------------------
// Kernel 2: FISTA. One wave per row; lane i holds asset i.
// ---------------------------------------------------------------------------
__global__ __launch_bounds__(256, 4) void fista_kernel(
    const float* __restrict__ sigma, const float* __restrict__ p,
    const float* __restrict__ step_ptr, float* __restrict__ w_out) {
  int lane = threadIdx.x & 63;
  int row = blockIdx.x * 4 + (threadIdx.x >> 6);

  // sigma column `lane` into registers (sigma symmetric; col == row)
  float sig[64];
#pragma unroll
  for (int i = 0; i < 64; ++i) sig[i] = sigma[i * 64 + lane];

  float step = step_ptr[0];
  float pj = p[row * 64 + lane];

  float w = 1.0f / 64.0f;
  float y = 1.0f / 64.0f;
  float t = 1.0f;

  for (int it = 0; it < N_FISTA; ++it) {
    float grad = matvec64(sig, y) + pj;
    float v = fmaf(-step, grad, y);

    // ---- simplex projection (Duchi): descending bitonic sort ----
    float u = v;
#pragma unroll
    for (int k = 2; k <= 64; k <<= 1) {
#pragma unroll
      for (int j = k >> 1; j >= 1; j >>= 1) {
        float other = __shfl_xor(u, j, 64);
        bool lower = (lane & j) == 0;
        bool dir_up = (lane & k) != 0;  // descending overall
        bool take_min = (dir_up == lower);
        u = take_min ? fminf(u, other) : fmaxf(u, other);
      }
    }
    // inclusive scan (cumsum over sorted-descending u)
    float css = u;
#pragma unroll
    for (int d = 1; d < 64; d <<= 1) {
      float tt = __shfl_up(css, d, 64);
      if (lane >= d) css += tt;
    }
    bool cond = (u + (1.0f - css) / (float)(lane + 1)) > 0.0f;
    unsigned long long m = __ballot(cond);
    int rho = __popcll(m) - 1;
    float css_rho = __shfl(css, rho, 64);
    float theta = (css_rho - 1.0f) / (float)(rho + 1);
    float wn = fmaxf(v - theta, 0.0f);

    float tn = 0.5f * (1.0f + sqrtf(fmaf(4.0f * t, t, 1.0f)));
    float c = (t - 1.0f) / tn;
    y = fmaf(c, wn - w, wn);
    w = wn;
    t = tn;
  }

  w_out[row * 64 + lane] = w;
}

extern "C" void kernel_launch(void* const* d_in, const int* in_sizes, int n_in,
                              void* d_out, int out_size, void* d_ws, size_t ws_size,
                              hipStream_t stream) {
  const float* x = (const float*)d_in[0];
  const float* W1 = (const float*)d_in[1];
  const float* b1 = (const float*)d_in[2];
  const float* W2 = (const float*)d_in[3];
  const float* b2 = (const float*)d_in[4];
  const float* W3 = (const float*)d_in[5];
  const float* b3 = (const float*)d_in[6];
  const float* sigma = (const float*)d_in[7];
  const float* gamma = (const float*)d_in[8];

  float* out = (float*)d_out;
  float* w_out = out;                         // [B, 64] weights
  float* mu_out = out + (size_t)B_ROWS * NA;  // [B, 64] mu

  float* p_ws = (float*)d_ws;                   // B*64 f32
  float* step_ws = p_ws + (size_t)B_ROWS * NA;  // 1 f32

  mlp_power_kernel<<<65, 256, 0, stream>>>(x, W1, b1, W2, b2, W3, b3, sigma,
                                           gamma, mu_out, p_ws, step_ws);
  fista_kernel<<<B_ROWS / 4, 256, 0, stream>>>(sigma, p_ws, step_ws, w_out);
}

// Round 3
// 1538.964 us; speedup vs baseline: 1.0641x; 1.0641x over previous
//
#include <hip/hip_runtime.h>
#include <hip/hip_bf16.h>

// MarkowitzPortfolioOptimizer: MLP -> mu, p = -gamma*mu; 200 FISTA iters of
// simplex-projected QP per batch row. B=16384, D=128, H1=32, H2=16, N=64.
// All tensors float32.
//
// R3: hand-lowered cross-lane ops in the FISTA loop.
//  - sort exchange xor1/2 -> DPP quad_perm (VALU-only)
//  - xor4/8/16 -> ds_swizzle immediate; xor32 -> ds_bpermute w/ precomp addr
//  - cumsum -> 6-instr DPP wave-scan idiom (row_shr + row_bcast15/31)
//  - take_min predicates + 1/(lane+1) precomputed outside the 200-loop
//  - dynamic shfl for css[rho] -> v_readlane (rho is wave-uniform)

#define B_ROWS 16384
#define NA 64
#define N_FISTA 200
#define N_POWER 256

__device__ __forceinline__ float rdlane(float v, int l) {
  return __int_as_float(__builtin_amdgcn_readlane(__float_as_int(v), l));
}

// DPP cross-lane move: result = value fetched per dpp_ctrl; masked/invalid -> 0.
#define DPPF(v, CTRL, RMASK) \
  __int_as_float(__builtin_amdgcn_update_dpp(0, __float_as_int(v), (CTRL), (RMASK), 0xF, false))
// ds_swizzle with immediate pattern (xor butterfly within 32-lane halves)
#define SWZF(v, IMM) __int_as_float(__builtin_amdgcn_ds_swizzle(__float_as_int(v), (IMM)))

// sum across 64 lanes (all lanes get result)
__device__ __forceinline__ float wave_sum64(float x) {
#pragma unroll
  for (int m = 32; m >= 1; m >>= 1) x += __shfl_xor(x, m, 64);
  return x;
}

// grad_lane = sum_i sig[i] * y_i, sig[] = column `lane` of sigma (64 VGPRs)
__device__ __forceinline__ float matvec64(const float* sig, float y) {
  float g0 = 0.f, g1 = 0.f, g2 = 0.f, g3 = 0.f;
#pragma unroll
  for (int i = 0; i < 64; i += 4) {
    g0 = fmaf(sig[i + 0], rdlane(y, i + 0), g0);
    g1 = fmaf(sig[i + 1], rdlane(y, i + 1), g1);
    g2 = fmaf(sig[i + 2], rdlane(y, i + 2), g2);
    g3 = fmaf(sig[i + 3], rdlane(y, i + 3), g3);
  }
  return (g0 + g1) + (g2 + g3);
}

// ---------------------------------------------------------------------------
// Kernel 1: blocks 0..63: MLP (one thread per row). block 64: power iteration
// for L = lambda_max(sigma); writes step = 1/L. p = -gamma*mu in f32 ws.
// ---------------------------------------------------------------------------
__global__ void mlp_power_kernel(const float* __restrict__ x,
                                 const float* __restrict__ W1, const float* __restrict__ b1,
                                 const float* __restrict__ W2, const float* __restrict__ b2,
                                 const float* __restrict__ W3, const float* __restrict__ b3,
                                 const float* __restrict__ sigma,
                                 const float* __restrict__ gamma,
                                 float* __restrict__ mu_out,  // d_out + B*NA
                                 float* __restrict__ p_out,   // ws
                                 float* __restrict__ step_out) {
  if (blockIdx.x == 64) {
    int tid = threadIdx.x;
    if (tid < 64) {
      int lane = tid;
      float sig[64];
#pragma unroll
      for (int i = 0; i < 64; ++i) sig[i] = sigma[i * 64 + lane];
      float v = 0.125f;
      for (int it = 0; it < N_POWER; ++it) {
        float u = matvec64(sig, v);
        float n2 = wave_sum64(u * u);
        v = u * rsqrtf(n2);
      }
      float u = matvec64(sig, v);
      float num = wave_sum64(v * u);
      float den = wave_sum64(v * v);
      if (lane == 0) step_out[0] = den / num;  // 1/L
    }
    return;
  }

  // ---- MLP ----
  __shared__ float sW1[128 * 32], sW2[32 * 16], sW3[16 * 64];
  __shared__ float sb1[32], sb2[16], sb3[64];
  int tid = threadIdx.x;
  for (int i = tid; i < 128 * 32; i += 256) sW1[i] = W1[i];
  for (int i = tid; i < 32 * 16; i += 256) sW2[i] = W2[i];
  for (int i = tid; i < 16 * 64; i += 256) sW3[i] = W3[i];
  if (tid < 32) sb1[tid] = b1[tid];
  if (tid < 16) sb2[tid] = b2[tid];
  if (tid < 64) sb3[tid] = b3[tid];
  __syncthreads();

  int row = blockIdx.x * 256 + tid;
  float gamma_f = gamma[0];

  float h1[32];
#pragma unroll
  for (int j = 0; j < 32; ++j) h1[j] = sb1[j];
  for (int k = 0; k < 128; k += 4) {
    float4 xk = *(const float4*)&x[row * 128 + k];
#pragma unroll
    for (int j = 0; j < 32; ++j) {
      h1[j] = fmaf(xk.x, sW1[(k + 0) * 32 + j], h1[j]);
      h1[j] = fmaf(xk.y, sW1[(k + 1) * 32 + j], h1[j]);
      h1[j] = fmaf(xk.z, sW1[(k + 2) * 32 + j], h1[j]);
      h1[j] = fmaf(xk.w, sW1[(k + 3) * 32 + j], h1[j]);
    }
  }
#pragma unroll
  for (int j = 0; j < 32; ++j) h1[j] = fmaxf(h1[j], 0.0f);

  float h2[16];
#pragma unroll
  for (int j = 0; j < 16; ++j) h2[j] = sb2[j];
#pragma unroll
  for (int k = 0; k < 32; ++k) {
#pragma unroll
    for (int j = 0; j < 16; ++j) h2[j] = fmaf(h1[k], sW2[k * 16 + j], h2[j]);
  }
#pragma unroll
  for (int j = 0; j < 16; ++j) h2[j] = fmaxf(h2[j], 0.0f);

  for (int o = 0; o < 64; ++o) {
    float mu = sb3[o];
#pragma unroll
    for (int k = 0; k < 16; ++k) mu = fmaf(h2[k], sW3[k * 64 + o], mu);
    mu_out[row * 64 + o] = mu;
    p_out[row * 64 + o] = -gamma_f * mu;
  }
}

// ---------------------------------------------------------------------------
// Kernel 2: FISTA. One wave per row; lane i holds asset i.
// ---------------------------------------------------------------------------
__global__ __launch_bounds__(256, 4) void fista_kernel(
    const float* __restrict__ sigma, const float* __restrict__ p,
    const float* __restrict__ step_ptr, float* __restrict__ w_out) {
  int lane = threadIdx.x & 63;
  int row = blockIdx.x * 4 + (threadIdx.x >> 6);

  // sigma column `lane` (sigma symmetric; col == row)
  float sig[64];
#pragma unroll
  for (int i = 0; i < 64; ++i) sig[i] = sigma[i * 64 + lane];

  float step = step_ptr[0];
  float pj = p[row * 64 + lane];

  // ---- iteration-invariant precompute ----
  float rcp_lane = 1.0f / (float)(lane + 1);   // exact-rounded, computed once
  int addr32 = ((lane ^ 32) << 2);             // bpermute byte addr for xor32
  // sort-stage select predicates: take_min = ((lane&k)!=0) == ((lane&j)==0)
#define TM(K, J) (((lane & (K)) != 0) == ((lane & (J)) == 0))
  const bool t2_1 = TM(2, 1);
  const bool t4_2 = TM(4, 2), t4_1 = TM(4, 1);
  const bool t8_4 = TM(8, 4), t8_2 = TM(8, 2), t8_1 = TM(8, 1);
  const bool t16_8 = TM(16, 8), t16_4 = TM(16, 4), t16_2 = TM(16, 2), t16_1 = TM(16, 1);
  const bool t32_16 = TM(32, 16), t32_8 = TM(32, 8), t32_4 = TM(32, 4), t32_2 = TM(32, 2),
             t32_1 = TM(32, 1);
  const bool t64_32 = TM(64, 32), t64_16 = TM(64, 16), t64_8 = TM(64, 8), t64_4 = TM(64, 4),
             t64_2 = TM(64, 2), t64_1 = TM(64, 1);
#undef TM

  float w = 1.0f / 64.0f;
  float y = 1.0f / 64.0f;
  float t = 1.0f;

  for (int it = 0; it < N_FISTA; ++it) {
    float grad = matvec64(sig, y) + pj;
    float v = fmaf(-step, grad, y);

    // ---- descending bitonic sort, hand-lowered exchanges ----
    float u = v;
    {
      float o;
#define EXCH(OVAL, TMV)        \
  do {                         \
    o = (OVAL);                \
    float mn = fminf(u, o);    \
    float mx = fmaxf(u, o);    \
    u = (TMV) ? mn : mx;       \
  } while (0)
#define X1(x) DPPF(x, 0xB1, 0xF)   /* quad_perm(1,0,3,2): lane^1 */
#define X2(x) DPPF(x, 0x4E, 0xF)   /* quad_perm(2,3,0,1): lane^2 */
#define X4(x) SWZF(x, 0x101F)
#define X8(x) SWZF(x, 0x201F)
#define X16(x) SWZF(x, 0x401F)
#define X32(x) __int_as_float(__builtin_amdgcn_ds_bpermute(addr32, __float_as_int(x)))
      EXCH(X1(u), t2_1);
      EXCH(X2(u), t4_2);
      EXCH(X1(u), t4_1);
      EXCH(X4(u), t8_4);
      EXCH(X2(u), t8_2);
      EXCH(X1(u), t8_1);
      EXCH(X8(u), t16_8);
      EXCH(X4(u), t16_4);
      EXCH(X2(u), t16_2);
      EXCH(X1(u), t16_1);
      EXCH(X16(u), t32_16);
      EXCH(X8(u), t32_8);
      EXCH(X4(u), t32_4);
      EXCH(X2(u), t32_2);
      EXCH(X1(u), t32_1);
      EXCH(X32(u), t64_32);
      EXCH(X16(u), t64_16);
      EXCH(X8(u), t64_8);
      EXCH(X4(u), t64_4);
      EXCH(X2(u), t64_2);
      EXCH(X1(u), t64_1);
#undef EXCH
    }

    // ---- inclusive scan via DPP wave-scan idiom (6 VALU, 0 DS) ----
    float css = u;
    css += DPPF(css, 0x111, 0xF);  // row_shr:1
    css += DPPF(css, 0x112, 0xF);  // row_shr:2
    css += DPPF(css, 0x114, 0xF);  // row_shr:4
    css += DPPF(css, 0x118, 0xF);  // row_shr:8
    css += DPPF(css, 0x142, 0xA);  // row_bcast15 -> rows 1,3
    css += DPPF(css, 0x143, 0xC);  // row_bcast31 -> rows 2,3

    // ---- rho / theta ----
    bool cond = fmaf(1.0f - css, rcp_lane, u) > 0.0f;
    unsigned long long m = __ballot(cond);
    int rho = __popcll(m) - 1;                 // wave-uniform
    float css_rho = rdlane(css, rho);
    float rcp_rho = rdlane(rcp_lane, rho);     // 1/(rho+1)
    float theta = (css_rho - 1.0f) * rcp_rho;
    float wn = fmaxf(v - theta, 0.0f);

    // ---- FISTA momentum ----
    float tn = 0.5f * (1.0f + sqrtf(fmaf(4.0f * t, t, 1.0f)));
    float c = (t - 1.0f) / tn;
    y = fmaf(c, wn - w, wn);
    w = wn;
    t = tn;
  }

  w_out[row * 64 + lane] = w;
}

extern "C" void kernel_launch(void* const* d_in, const int* in_sizes, int n_in,
                              void* d_out, int out_size, void* d_ws, size_t ws_size,
                              hipStream_t stream) {
  const float* x = (const float*)d_in[0];
  const float* W1 = (const float*)d_in[1];
  const float* b1 = (const float*)d_in[2];
  const float* W2 = (const float*)d_in[3];
  const float* b2 = (const float*)d_in[4];
  const float* W3 = (const float*)d_in[5];
  const float* b3 = (const float*)d_in[6];
  const float* sigma = (const float*)d_in[7];
  const float* gamma = (const float*)d_in[8];

  float* out = (float*)d_out;
  float* w_out = out;                         // [B, 64] weights
  float* mu_out = out + (size_t)B_ROWS * NA;  // [B, 64] mu

  float* p_ws = (float*)d_ws;                   // B*64 f32
  float* step_ws = p_ws + (size_t)B_ROWS * NA;  // 1 f32

  mlp_power_kernel<<<65, 256, 0, stream>>>(x, W1, b1, W2, b2, W3, b3, sigma,
                                           gamma, mu_out, p_ws, step_ws);
  fista_kernel<<<B_ROWS / 4, 256, 0, stream>>>(sigma, p_ws, step_ws, w_out);
}

// Round 4
// 605.418 us; speedup vs baseline: 2.7050x; 2.5420x over previous
//
#include <hip/hip_runtime.h>
#include <hip/hip_bf16.h>

// MarkowitzPortfolioOptimizer. All tensors f32.
// R4 redesign: FISTA matvec via bf16 MFMA (hi+lo split for ~f32 accuracy),
// 16 rows per wave; simplex projection via sortless Michelot (Newton on
// f(theta)=1) with 4-lane-group bpermute reductions.

#define B_ROWS 16384
#define NA 64
#define N_FISTA 200
#define N_POWER 256

typedef __attribute__((ext_vector_type(4))) float f32x4;
typedef __attribute__((ext_vector_type(8))) short s16x8;
typedef __attribute__((ext_vector_type(4))) int i32x4;

union V4 {
  i32x4 i;
  s16x8 s;
  f32x4 f;
};

__device__ __forceinline__ unsigned fu(float x) { return __float_as_uint(x); }
__device__ __forceinline__ float uf(unsigned x) { return __uint_as_float(x); }

__device__ __forceinline__ float rdlane(float v, int l) {
  return __int_as_float(__builtin_amdgcn_readlane(__float_as_int(v), l));
}

__device__ __forceinline__ float wave_sum64(float x) {
#pragma unroll
  for (int m = 32; m >= 1; m >>= 1) x += __shfl_xor(x, m, 64);
  return x;
}

__device__ __forceinline__ float matvec64(const float* sig, float y) {
  float g0 = 0.f, g1 = 0.f, g2 = 0.f, g3 = 0.f;
#pragma unroll
  for (int i = 0; i < 64; i += 4) {
    g0 = fmaf(sig[i + 0], rdlane(y, i + 0), g0);
    g1 = fmaf(sig[i + 1], rdlane(y, i + 1), g1);
    g2 = fmaf(sig[i + 2], rdlane(y, i + 2), g2);
    g3 = fmaf(sig[i + 3], rdlane(y, i + 3), g3);
  }
  return (g0 + g1) + (g2 + g3);
}

// ---------------------------------------------------------------------------
// Kernel 1: blocks 0..63: MLP. block 64: power iteration -> step = 1/L.
// ---------------------------------------------------------------------------
__global__ void mlp_power_kernel(const float* __restrict__ x,
                                 const float* __restrict__ W1, const float* __restrict__ b1,
                                 const float* __restrict__ W2, const float* __restrict__ b2,
                                 const float* __restrict__ W3, const float* __restrict__ b3,
                                 const float* __restrict__ sigma,
                                 const float* __restrict__ gamma,
                                 float* __restrict__ mu_out,
                                 float* __restrict__ p_out,
                                 float* __restrict__ step_out) {
  if (blockIdx.x == 64) {
    int tid = threadIdx.x;
    if (tid < 64) {
      int lane = tid;
      float sig[64];
#pragma unroll
      for (int i = 0; i < 64; ++i) sig[i] = sigma[i * 64 + lane];
      float v = 0.125f;
      for (int it = 0; it < N_POWER; ++it) {
        float u = matvec64(sig, v);
        float n2 = wave_sum64(u * u);
        v = u * rsqrtf(n2);
      }
      float u = matvec64(sig, v);
      float num = wave_sum64(v * u);
      float den = wave_sum64(v * v);
      if (lane == 0) step_out[0] = den / num;  // 1/L
    }
    return;
  }

  __shared__ float sW1[128 * 32], sW2[32 * 16], sW3[16 * 64];
  __shared__ float sb1[32], sb2[16], sb3[64];
  int tid = threadIdx.x;
  for (int i = tid; i < 128 * 32; i += 256) sW1[i] = W1[i];
  for (int i = tid; i < 32 * 16; i += 256) sW2[i] = W2[i];
  for (int i = tid; i < 16 * 64; i += 256) sW3[i] = W3[i];
  if (tid < 32) sb1[tid] = b1[tid];
  if (tid < 16) sb2[tid] = b2[tid];
  if (tid < 64) sb3[tid] = b3[tid];
  __syncthreads();

  int row = blockIdx.x * 256 + tid;
  float gamma_f = gamma[0];

  float h1[32];
#pragma unroll
  for (int j = 0; j < 32; ++j) h1[j] = sb1[j];
  for (int k = 0; k < 128; k += 4) {
    f32x4 xk = *(const f32x4*)&x[row * 128 + k];
#pragma unroll
    for (int j = 0; j < 32; ++j) {
      h1[j] = fmaf(xk.x, sW1[(k + 0) * 32 + j], h1[j]);
      h1[j] = fmaf(xk.y, sW1[(k + 1) * 32 + j], h1[j]);
      h1[j] = fmaf(xk.z, sW1[(k + 2) * 32 + j], h1[j]);
      h1[j] = fmaf(xk.w, sW1[(k + 3) * 32 + j], h1[j]);
    }
  }
#pragma unroll
  for (int j = 0; j < 32; ++j) h1[j] = fmaxf(h1[j], 0.0f);

  float h2[16];
#pragma unroll
  for (int j = 0; j < 16; ++j) h2[j] = sb2[j];
#pragma unroll
  for (int k = 0; k < 32; ++k) {
#pragma unroll
    for (int j = 0; j < 16; ++j) h2[j] = fmaf(h1[k], sW2[k * 16 + j], h2[j]);
  }
#pragma unroll
  for (int j = 0; j < 16; ++j) h2[j] = fmaxf(h2[j], 0.0f);

  for (int o = 0; o < 64; ++o) {
    float mu = sb3[o];
#pragma unroll
    for (int k = 0; k < 16; ++k) mu = fmaf(h2[k], sW3[k * 64 + o], mu);
    mu_out[row * 64 + o] = mu;
    p_out[row * 64 + o] = -gamma_f * mu;
  }
}

// ---------------------------------------------------------------------------
// Kernel 2: FISTA, 16 rows per wave via MFMA.
//   G(64x16) = Sigma(64x64) @ Y^T(64x16) + P, bf16 hi/lo split (3 pairings).
//   C-layout: lane L holds row r=L&15, assets j = 16t + 4(L>>4) + reg.
//   Michelot projection per 4-lane group {r, r+16, r+32, r+48}.
// ---------------------------------------------------------------------------
__global__ __launch_bounds__(256, 1) void fista_kernel(
    const float* __restrict__ sigma, const float* __restrict__ p,
    const float* __restrict__ step_ptr, float* __restrict__ w_out) {
  const int tid = threadIdx.x;
  const int wv = tid >> 6;
  const int lane = tid & 63;
  const int r = lane & 15;   // batch row (C/B layout) OR Sigma row within M-tile (A layout)
  const int q = lane >> 4;   // quad index
  const int rowbase = (blockIdx.x * 4 + wv) * 16;

  // per-wave private LDS: [wave][plane(hi/lo)][row 16][72 bf16] (72 => 144B rows, 16B aligned)
  __shared__ __align__(16) unsigned short y_lds[4][2][16][72];

  // ---- one-time: A-frags (Sigma hi/lo), bf16-packed. A[m=r][k=8q+jj+32s] = sigma[16t+r][k]
  s16x8 a_hi[8], a_lo[8];  // [t*2+s]
#pragma unroll
  for (int t = 0; t < 4; ++t) {
#pragma unroll
    for (int s = 0; s < 2; ++s) {
      const float* sp = sigma + (16 * t + r) * 64 + 32 * s + 8 * q;
      f32x4 A0 = *(const f32x4*)sp;
      f32x4 A1 = *(const f32x4*)(sp + 4);
      float e[8] = {A0.x, A0.y, A0.z, A0.w, A1.x, A1.y, A1.z, A1.w};
      unsigned h[8], lu[8];
#pragma unroll
      for (int k = 0; k < 8; ++k) {
        h[k] = fu(e[k]) & 0xFFFF0000u;          // hi = truncate
        float lo = e[k] - uf(h[k]);             // exact residual
        lu[k] = fu(lo) + 0x8000u;               // round lo
      }
      V4 hv, lv;
      hv.i = i32x4{(int)((h[0] >> 16) | h[1]), (int)((h[2] >> 16) | h[3]),
                   (int)((h[4] >> 16) | h[5]), (int)((h[6] >> 16) | h[7])};
      lv.i = i32x4{(int)((lu[0] >> 16) | (lu[1] & 0xFFFF0000u)),
                   (int)((lu[2] >> 16) | (lu[3] & 0xFFFF0000u)),
                   (int)((lu[4] >> 16) | (lu[5] & 0xFFFF0000u)),
                   (int)((lu[6] >> 16) | (lu[7] & 0xFFFF0000u))};
      a_hi[t * 2 + s] = hv.s;
      a_lo[t * 2 + s] = lv.s;
    }
  }

  // ---- one-time: P-frags in C layout: p[rowbase+r][16t+4q+reg]
  f32x4 pf[4];
#pragma unroll
  for (int t = 0; t < 4; ++t)
    pf[t] = *(const f32x4*)(p + (rowbase + r) * 64 + 16 * t + 4 * q);

  const float step = step_ptr[0];
  const float nstep = -step;

  // bpermute byte addrs for group partners (lanes r+16k) and LDS ptrs
  const int a16 = ((lane ^ 16) << 2);
  const int a32 = ((lane ^ 32) << 2);
  const int a48 = ((lane ^ 48) << 2);
  unsigned short* wp = &y_lds[wv][0][r][4 * q];        // write base (j = 16t+4q)
  const unsigned short* rp = &y_lds[wv][0][r][8 * q];  // read base (k = 8q)

  float w[16], y[16];
#pragma unroll
  for (int i = 0; i < 16; ++i) { w[i] = 1.0f / 64.0f; y[i] = 1.0f / 64.0f; }
  float t_m = 1.0f;

#pragma unroll 1
  for (int it = 0; it < N_FISTA; ++it) {
    // ---- 1. pack y (hi/lo bf16) and write to LDS (b64 per tile per plane)
#pragma unroll
    for (int t = 0; t < 4; ++t) {
      unsigned h0 = fu(y[4 * t + 0]) & 0xFFFF0000u;
      unsigned h1 = fu(y[4 * t + 1]) & 0xFFFF0000u;
      unsigned h2 = fu(y[4 * t + 2]) & 0xFFFF0000u;
      unsigned h3 = fu(y[4 * t + 3]) & 0xFFFF0000u;
      unsigned lu0 = fu(y[4 * t + 0] - uf(h0)) + 0x8000u;
      unsigned lu1 = fu(y[4 * t + 1] - uf(h1)) + 0x8000u;
      unsigned lu2 = fu(y[4 * t + 2] - uf(h2)) + 0x8000u;
      unsigned lu3 = fu(y[4 * t + 3] - uf(h3)) + 0x8000u;
      unsigned hp0 = (h0 >> 16) | h1;
      unsigned hp1 = (h2 >> 16) | h3;
      unsigned lp0 = (lu0 >> 16) | (lu1 & 0xFFFF0000u);
      unsigned lp1 = (lu2 >> 16) | (lu3 & 0xFFFF0000u);
      *(unsigned long long*)(wp + 16 * t) =
          ((unsigned long long)hp1 << 32) | hp0;
      *(unsigned long long*)(wp + 16 * t + 1152) =
          ((unsigned long long)lp1 << 32) | lp0;
    }
    __asm__ __volatile__("" ::: "memory");

    // ---- 2. read B-frags: B[k=8q+jj+32s][n=r] = y[r][k]
    V4 bh0, bh1, bl0, bl1;
    bh0.i = *(const i32x4*)(rp);
    bh1.i = *(const i32x4*)(rp + 32);
    bl0.i = *(const i32x4*)(rp + 1152);
    bl1.i = *(const i32x4*)(rp + 1152 + 32);
    __asm__ __volatile__("" ::: "memory");

    // ---- 3. grad = Sigma@Y^T + P  (hi*hi + hi*lo + lo*hi)
    float v[16];
#pragma unroll
    for (int t = 0; t < 4; ++t) {
      f32x4 acc = pf[t];
      acc = __builtin_amdgcn_mfma_f32_16x16x32_bf16(a_hi[t * 2 + 0], bh0.s, acc, 0, 0, 0);
      acc = __builtin_amdgcn_mfma_f32_16x16x32_bf16(a_hi[t * 2 + 1], bh1.s, acc, 0, 0, 0);
      acc = __builtin_amdgcn_mfma_f32_16x16x32_bf16(a_lo[t * 2 + 0], bh0.s, acc, 0, 0, 0);
      acc = __builtin_amdgcn_mfma_f32_16x16x32_bf16(a_lo[t * 2 + 1], bh1.s, acc, 0, 0, 0);
      acc = __builtin_amdgcn_mfma_f32_16x16x32_bf16(a_hi[t * 2 + 0], bl0.s, acc, 0, 0, 0);
      acc = __builtin_amdgcn_mfma_f32_16x16x32_bf16(a_hi[t * 2 + 1], bl1.s, acc, 0, 0, 0);
      v[4 * t + 0] = fmaf(nstep, acc.x, y[4 * t + 0]);
      v[4 * t + 1] = fmaf(nstep, acc.y, y[4 * t + 1]);
      v[4 * t + 2] = fmaf(nstep, acc.z, y[4 * t + 2]);
      v[4 * t + 3] = fmaf(nstep, acc.w, y[4 * t + 3]);
    }

    // ---- 4. Michelot projection per group (row r across lanes r+16k)
    float s0 = ((v[0] + v[1]) + (v[2] + v[3])) + ((v[4] + v[5]) + (v[6] + v[7]));
    float s1 = ((v[8] + v[9]) + (v[10] + v[11])) + ((v[12] + v[13]) + (v[14] + v[15]));
    float S = s0 + s1;
    {
      float x16 = __int_as_float(__builtin_amdgcn_ds_bpermute(a16, __float_as_int(S)));
      float x32 = __int_as_float(__builtin_amdgcn_ds_bpermute(a32, __float_as_int(S)));
      float x48 = __int_as_float(__builtin_amdgcn_ds_bpermute(a48, __float_as_int(S)));
      S = (S + x16) + (x32 + x48);
    }
    float theta = (S - 1.0f) * 0.015625f;
    int n_prev = 64;
#pragma unroll 1
    for (int mm = 0; mm < 24; ++mm) {
      float f = 0.0f;
      int sc = 0;
#pragma unroll
      for (int i = 0; i < 16; ++i) {
        float d = v[i] - theta;
        f += fmaxf(d, 0.0f);
        sc += (__float_as_int(d) >> 31);  // -1 if d<0
      }
      float f16 = __int_as_float(__builtin_amdgcn_ds_bpermute(a16, __float_as_int(f)));
      float f32_ = __int_as_float(__builtin_amdgcn_ds_bpermute(a32, __float_as_int(f)));
      float f48 = __int_as_float(__builtin_amdgcn_ds_bpermute(a48, __float_as_int(f)));
      int c16 = __builtin_amdgcn_ds_bpermute(a16, sc);
      int c32 = __builtin_amdgcn_ds_bpermute(a32, sc);
      int c48 = __builtin_amdgcn_ds_bpermute(a48, sc);
      f = (f + f16) + (f32_ + f48);
      sc = (sc + c16) + (c32 + c48);
      int n = 64 + sc;
      theta += (f - 1.0f) * __builtin_amdgcn_rcpf((float)n);
      bool changed = (n != n_prev);
      n_prev = n;
      if (__ballot(changed) == 0ull) break;
    }

    // ---- 5. project + momentum
    float tn = 0.5f * (1.0f + sqrtf(fmaf(4.0f * t_m, t_m, 1.0f)));
    float c = (t_m - 1.0f) * __builtin_amdgcn_rcpf(tn);
#pragma unroll
    for (int i = 0; i < 16; ++i) {
      float wn = fmaxf(v[i] - theta, 0.0f);
      y[i] = fmaf(c, wn - w[i], wn);
      w[i] = wn;
    }
    t_m = tn;
  }

  // ---- store (C layout -> row-major): w[rowbase+r][16t+4q+reg]
#pragma unroll
  for (int t = 0; t < 4; ++t) {
    f32x4 st{w[4 * t + 0], w[4 * t + 1], w[4 * t + 2], w[4 * t + 3]};
    *(f32x4*)(w_out + (rowbase + r) * 64 + 16 * t + 4 * q) = st;
  }
}

extern "C" void kernel_launch(void* const* d_in, const int* in_sizes, int n_in,
                              void* d_out, int out_size, void* d_ws, size_t ws_size,
                              hipStream_t stream) {
  const float* x = (const float*)d_in[0];
  const float* W1 = (const float*)d_in[1];
  const float* b1 = (const float*)d_in[2];
  const float* W2 = (const float*)d_in[3];
  const float* b2 = (const float*)d_in[4];
  const float* W3 = (const float*)d_in[5];
  const float* b3 = (const float*)d_in[6];
  const float* sigma = (const float*)d_in[7];
  const float* gamma = (const float*)d_in[8];

  float* out = (float*)d_out;
  float* w_out = out;                         // [B, 64] weights
  float* mu_out = out + (size_t)B_ROWS * NA;  // [B, 64] mu

  float* p_ws = (float*)d_ws;                   // B*64 f32
  float* step_ws = p_ws + (size_t)B_ROWS * NA;  // 1 f32

  mlp_power_kernel<<<65, 256, 0, stream>>>(x, W1, b1, W2, b2, W3, b3, sigma,
                                           gamma, mu_out, p_ws, step_ws);
  fista_kernel<<<B_ROWS / 64, 256, 0, stream>>>(sigma, p_ws, step_ws, w_out);
}

// Round 5
// 313.777 us; speedup vs baseline: 5.2192x; 1.9295x over previous
//
#include <hip/hip_runtime.h>
#include <hip/hip_bf16.h>

// MarkowitzPortfolioOptimizer. All tensors f32.
// R5: warm-started Michelot (theta/n persist across FISTA iters), XOR-swizzled
// LDS y-transpose (conflict-free b128 reads, 2-way b64 writes), v_perm bf16
// packing, sparse normalization in the power iteration.

#define B_ROWS 16384
#define NA 64
#define N_FISTA 200
#define N_POWER 256

typedef __attribute__((ext_vector_type(4))) float f32x4;
typedef __attribute__((ext_vector_type(8))) short s16x8;
typedef __attribute__((ext_vector_type(4))) int i32x4;

union V4 {
  i32x4 i;
  s16x8 s;
  f32x4 f;
};

__device__ __forceinline__ unsigned fu(float x) { return __float_as_uint(x); }
__device__ __forceinline__ float uf(unsigned x) { return __uint_as_float(x); }

__device__ __forceinline__ float rdlane(float v, int l) {
  return __int_as_float(__builtin_amdgcn_readlane(__float_as_int(v), l));
}

__device__ __forceinline__ float wave_sum64(float x) {
#pragma unroll
  for (int m = 32; m >= 1; m >>= 1) x += __shfl_xor(x, m, 64);
  return x;
}

__device__ __forceinline__ float matvec64(const float* sig, float y) {
  float g0 = 0.f, g1 = 0.f, g2 = 0.f, g3 = 0.f;
#pragma unroll
  for (int i = 0; i < 64; i += 4) {
    g0 = fmaf(sig[i + 0], rdlane(y, i + 0), g0);
    g1 = fmaf(sig[i + 1], rdlane(y, i + 1), g1);
    g2 = fmaf(sig[i + 2], rdlane(y, i + 2), g2);
    g3 = fmaf(sig[i + 3], rdlane(y, i + 3), g3);
  }
  return (g0 + g1) + (g2 + g3);
}

// ---------------------------------------------------------------------------
// Kernel 1: blocks 0..63: MLP. block 64: power iteration -> step = 1/L.
// ---------------------------------------------------------------------------
__global__ void mlp_power_kernel(const float* __restrict__ x,
                                 const float* __restrict__ W1, const float* __restrict__ b1,
                                 const float* __restrict__ W2, const float* __restrict__ b2,
                                 const float* __restrict__ W3, const float* __restrict__ b3,
                                 const float* __restrict__ sigma,
                                 const float* __restrict__ gamma,
                                 float* __restrict__ mu_out,
                                 float* __restrict__ p_out,
                                 float* __restrict__ step_out) {
  if (blockIdx.x == 64) {
    int tid = threadIdx.x;
    if (tid < 64) {
      int lane = tid;
      float sig[64];
#pragma unroll
      for (int i = 0; i < 64; ++i) sig[i] = sigma[i * 64 + lane];
      float v = 0.125f;
      // normalize only every 16 iters (growth ~4^16 ~ 4e9, f32-safe)
      for (int it = 0; it < N_POWER; ++it) {
        v = matvec64(sig, v);
        if ((it & 15) == 15) {
          float n2 = wave_sum64(v * v);
          v *= rsqrtf(n2);
        }
      }
      float n2 = wave_sum64(v * v);
      v *= rsqrtf(n2);
      float u = matvec64(sig, v);
      float num = wave_sum64(v * u);  // Rayleigh quotient (||v||=1)
      if (lane == 0) step_out[0] = 1.0f / num;
    }
    return;
  }

  __shared__ float sW1[128 * 32], sW2[32 * 16], sW3[16 * 64];
  __shared__ float sb1[32], sb2[16], sb3[64];
  int tid = threadIdx.x;
  for (int i = tid; i < 128 * 32; i += 256) sW1[i] = W1[i];
  for (int i = tid; i < 32 * 16; i += 256) sW2[i] = W2[i];
  for (int i = tid; i < 16 * 64; i += 256) sW3[i] = W3[i];
  if (tid < 32) sb1[tid] = b1[tid];
  if (tid < 16) sb2[tid] = b2[tid];
  if (tid < 64) sb3[tid] = b3[tid];
  __syncthreads();

  int row = blockIdx.x * 256 + tid;
  float gamma_f = gamma[0];

  float h1[32];
#pragma unroll
  for (int j = 0; j < 32; ++j) h1[j] = sb1[j];
  for (int k = 0; k < 128; k += 4) {
    f32x4 xk = *(const f32x4*)&x[row * 128 + k];
#pragma unroll
    for (int j = 0; j < 32; ++j) {
      h1[j] = fmaf(xk.x, sW1[(k + 0) * 32 + j], h1[j]);
      h1[j] = fmaf(xk.y, sW1[(k + 1) * 32 + j], h1[j]);
      h1[j] = fmaf(xk.z, sW1[(k + 2) * 32 + j], h1[j]);
      h1[j] = fmaf(xk.w, sW1[(k + 3) * 32 + j], h1[j]);
    }
  }
#pragma unroll
  for (int j = 0; j < 32; ++j) h1[j] = fmaxf(h1[j], 0.0f);

  float h2[16];
#pragma unroll
  for (int j = 0; j < 16; ++j) h2[j] = sb2[j];
#pragma unroll
  for (int k = 0; k < 32; ++k) {
#pragma unroll
    for (int j = 0; j < 16; ++j) h2[j] = fmaf(h1[k], sW2[k * 16 + j], h2[j]);
  }
#pragma unroll
  for (int j = 0; j < 16; ++j) h2[j] = fmaxf(h2[j], 0.0f);

  for (int o = 0; o < 64; ++o) {
    float mu = sb3[o];
#pragma unroll
    for (int k = 0; k < 16; ++k) mu = fmaf(h2[k], sW3[k * 64 + o], mu);
    mu_out[row * 64 + o] = mu;
    p_out[row * 64 + o] = -gamma_f * mu;
  }
}

// ---------------------------------------------------------------------------
// Kernel 2: FISTA, 16 rows per wave via MFMA (hi/lo bf16 split).
//   C-layout: lane L (r=L&15, q=L>>4) holds row rowbase+r, assets 16t+4q+reg.
//   y relayout C->B through XOR-swizzled LDS:
//     physical 16B block of logical block lb in row r: lb ^ (r&7); row stride
//     128B (32 dwords == 0 mod 32 banks) -> b128 reads conflict-free per
//     8-lane cohort, b64 writes 2-way (free).
//   Michelot projection per 4-lane group, theta/n warm-started across iters.
// ---------------------------------------------------------------------------
__global__ __launch_bounds__(256, 1) void fista_kernel(
    const float* __restrict__ sigma, const float* __restrict__ p,
    const float* __restrict__ step_ptr, float* __restrict__ w_out) {
  const int tid = threadIdx.x;
  const int wv = tid >> 6;
  const int lane = tid & 63;
  const int r = lane & 15;
  const int q = lane >> 4;
  const int rowbase = (blockIdx.x * 4 + wv) * 16;

  // [wave][plane][16 rows][64 bf16], 4KB/wave, XOR-swizzled blocks
  __shared__ __align__(16) unsigned short y_lds[4 * 2 * 16 * 64];

  // ---- one-time: A-frags (Sigma hi/lo). A[m=r][k=8q+jj+32s] = sigma[16t+r][k]
  s16x8 a_hi[8], a_lo[8];  // [t*2+s]
#pragma unroll
  for (int t = 0; t < 4; ++t) {
#pragma unroll
    for (int s = 0; s < 2; ++s) {
      const float* sp = sigma + (16 * t + r) * 64 + 32 * s + 8 * q;
      f32x4 A0 = *(const f32x4*)sp;
      f32x4 A1 = *(const f32x4*)(sp + 4);
      float e[8] = {A0.x, A0.y, A0.z, A0.w, A1.x, A1.y, A1.z, A1.w};
      unsigned h[8], lu[8];
#pragma unroll
      for (int k = 0; k < 8; ++k) {
        h[k] = fu(e[k]) & 0xFFFF0000u;  // hi = truncate (exact residual split)
        float lo = e[k] - uf(h[k]);
        lu[k] = fu(lo) + 0x8000u;       // round lo to bf16
      }
      V4 hv, lv;
      hv.i = i32x4{(int)((h[0] >> 16) | h[1]), (int)((h[2] >> 16) | h[3]),
                   (int)((h[4] >> 16) | h[5]), (int)((h[6] >> 16) | h[7])};
      lv.i = i32x4{(int)((lu[0] >> 16) | (lu[1] & 0xFFFF0000u)),
                   (int)((lu[2] >> 16) | (lu[3] & 0xFFFF0000u)),
                   (int)((lu[4] >> 16) | (lu[5] & 0xFFFF0000u)),
                   (int)((lu[6] >> 16) | (lu[7] & 0xFFFF0000u))};
      a_hi[t * 2 + s] = hv.s;
      a_lo[t * 2 + s] = lv.s;
    }
  }

  // ---- one-time: P-frags in C layout
  f32x4 pf[4];
#pragma unroll
  for (int t = 0; t < 4; ++t)
    pf[t] = *(const f32x4*)(p + (rowbase + r) * 64 + 16 * t + 4 * q);

  const float step = step_ptr[0];
  const float nstep = -step;

  const int a16 = ((lane ^ 16) << 2);
  const int a32 = ((lane ^ 32) << 2);
  const int a48 = ((lane ^ 48) << 2);

  // swizzled LDS pointers (shorts). wave base + row base.
  const int swz = r & 7;
  unsigned short* const wbase = &y_lds[wv * 2048 + r * 64];
  // write ptrs per tile t (hi plane; lo = +1024 shorts)
  unsigned short* wpt[4];
#pragma unroll
  for (int t = 0; t < 4; ++t)
    wpt[t] = wbase + (((2 * t + (q >> 1)) ^ swz) * 8 + (q & 1) * 4);
  // read ptrs for s=0,1
  const unsigned short* rp0 = wbase + ((q ^ swz) * 8);
  const unsigned short* rp1 = wbase + (((4 + q) ^ swz) * 8);

  float w[16], y[16];
#pragma unroll
  for (int i = 0; i < 16; ++i) { w[i] = 1.0f / 64.0f; y[i] = 1.0f / 64.0f; }
  float t_m = 1.0f;
  float theta = 0.0f;  // warm-started across FISTA iters (exact for w0)
  int n_prev = 64;

#pragma unroll 1
  for (int it = 0; it < N_FISTA; ++it) {
    // ---- 1. pack y (hi trunc / lo rne) via v_perm, write to LDS
#pragma unroll
    for (int t = 0; t < 4; ++t) {
      unsigned y0 = fu(y[4 * t + 0]), y1 = fu(y[4 * t + 1]);
      unsigned y2 = fu(y[4 * t + 2]), y3 = fu(y[4 * t + 3]);
      unsigned hp0 = __builtin_amdgcn_perm(y1, y0, 0x07060302u);
      unsigned hp1 = __builtin_amdgcn_perm(y3, y2, 0x07060302u);
      unsigned l0 = fu(y[4 * t + 0] - uf(y0 & 0xFFFF0000u)) + 0x8000u;
      unsigned l1 = fu(y[4 * t + 1] - uf(y1 & 0xFFFF0000u)) + 0x8000u;
      unsigned l2 = fu(y[4 * t + 2] - uf(y2 & 0xFFFF0000u)) + 0x8000u;
      unsigned l3 = fu(y[4 * t + 3] - uf(y3 & 0xFFFF0000u)) + 0x8000u;
      unsigned lp0 = __builtin_amdgcn_perm(l1, l0, 0x07060302u);
      unsigned lp1 = __builtin_amdgcn_perm(l3, l2, 0x07060302u);
      *(unsigned long long*)(wpt[t]) = ((unsigned long long)hp1 << 32) | hp0;
      *(unsigned long long*)(wpt[t] + 1024) = ((unsigned long long)lp1 << 32) | lp0;
    }
    __asm__ __volatile__("" ::: "memory");

    // ---- 2. read B-frags
    V4 bh0, bh1, bl0, bl1;
    bh0.i = *(const i32x4*)(rp0);
    bh1.i = *(const i32x4*)(rp1);
    bl0.i = *(const i32x4*)(rp0 + 1024);
    bl1.i = *(const i32x4*)(rp1 + 1024);
    __asm__ __volatile__("" ::: "memory");

    // ---- 3. grad = Sigma@Y^T + P  (hi*hi + lo*hi + hi*lo)
    float v[16];
#pragma unroll
    for (int t = 0; t < 4; ++t) {
      f32x4 acc = pf[t];
      acc = __builtin_amdgcn_mfma_f32_16x16x32_bf16(a_hi[t * 2 + 0], bh0.s, acc, 0, 0, 0);
      acc = __builtin_amdgcn_mfma_f32_16x16x32_bf16(a_hi[t * 2 + 1], bh1.s, acc, 0, 0, 0);
      acc = __builtin_amdgcn_mfma_f32_16x16x32_bf16(a_lo[t * 2 + 0], bh0.s, acc, 0, 0, 0);
      acc = __builtin_amdgcn_mfma_f32_16x16x32_bf16(a_lo[t * 2 + 1], bh1.s, acc, 0, 0, 0);
      acc = __builtin_amdgcn_mfma_f32_16x16x32_bf16(a_hi[t * 2 + 0], bl0.s, acc, 0, 0, 0);
      acc = __builtin_amdgcn_mfma_f32_16x16x32_bf16(a_hi[t * 2 + 1], bl1.s, acc, 0, 0, 0);
      v[4 * t + 0] = fmaf(nstep, acc.x, y[4 * t + 0]);
      v[4 * t + 1] = fmaf(nstep, acc.y, y[4 * t + 1]);
      v[4 * t + 2] = fmaf(nstep, acc.z, y[4 * t + 2]);
      v[4 * t + 3] = fmaf(nstep, acc.w, y[4 * t + 3]);
    }

    // ---- 4. Michelot/Newton projection, warm-started theta
#pragma unroll 1
    for (int mm = 0; mm < 24; ++mm) {
      float f = 0.0f;
      int sc = 0;
#pragma unroll
      for (int i = 0; i < 16; ++i) {
        float d = v[i] - theta;
        f += fmaxf(d, 0.0f);
        sc += (__float_as_int(d) >> 31);  // -1 if d<0
      }
      float f16 = __int_as_float(__builtin_amdgcn_ds_bpermute(a16, __float_as_int(f)));
      float f32_ = __int_as_float(__builtin_amdgcn_ds_bpermute(a32, __float_as_int(f)));
      float f48 = __int_as_float(__builtin_amdgcn_ds_bpermute(a48, __float_as_int(f)));
      int c16 = __builtin_amdgcn_ds_bpermute(a16, sc);
      int c32 = __builtin_amdgcn_ds_bpermute(a32, sc);
      int c48 = __builtin_amdgcn_ds_bpermute(a48, sc);
      f = (f + f16) + (f32_ + f48);
      sc = (sc + c16) + (c32 + c48);
      int n = 64 + sc;
      int ng = n > 1 ? n : 1;  // n==0 guard (theta above all v)
      theta += (f - 1.0f) * __builtin_amdgcn_rcpf((float)ng);
      bool changed = (n != n_prev);
      n_prev = n;
      if (__ballot(changed) == 0ull) break;
    }

    // ---- 5. project + momentum
    float tn = 0.5f * (1.0f + sqrtf(fmaf(4.0f * t_m, t_m, 1.0f)));
    float c = (t_m - 1.0f) * __builtin_amdgcn_rcpf(tn);
#pragma unroll
    for (int i = 0; i < 16; ++i) {
      float wn = fmaxf(v[i] - theta, 0.0f);
      y[i] = fmaf(c, wn - w[i], wn);
      w[i] = wn;
    }
    t_m = tn;
  }

  // ---- store (C layout -> row-major)
#pragma unroll
  for (int t = 0; t < 4; ++t) {
    f32x4 st{w[4 * t + 0], w[4 * t + 1], w[4 * t + 2], w[4 * t + 3]};
    *(f32x4*)(w_out + (rowbase + r) * 64 + 16 * t + 4 * q) = st;
  }
}

extern "C" void kernel_launch(void* const* d_in, const int* in_sizes, int n_in,
                              void* d_out, int out_size, void* d_ws, size_t ws_size,
                              hipStream_t stream) {
  const float* x = (const float*)d_in[0];
  const float* W1 = (const float*)d_in[1];
  const float* b1 = (const float*)d_in[2];
  const float* W2 = (const float*)d_in[3];
  const float* b2 = (const float*)d_in[4];
  const float* W3 = (const float*)d_in[5];
  const float* b3 = (const float*)d_in[6];
  const float* sigma = (const float*)d_in[7];
  const float* gamma = (const float*)d_in[8];

  float* out = (float*)d_out;
  float* w_out = out;                         // [B, 64] weights
  float* mu_out = out + (size_t)B_ROWS * NA;  // [B, 64] mu

  float* p_ws = (float*)d_ws;                   // B*64 f32
  float* step_ws = p_ws + (size_t)B_ROWS * NA;  // 1 f32

  mlp_power_kernel<<<65, 256, 0, stream>>>(x, W1, b1, W2, b2, W3, b3, sigma,
                                           gamma, mu_out, p_ws, step_ws);
  fista_kernel<<<B_ROWS / 64, 256, 0, stream>>>(sigma, p_ws, step_ws, w_out);
}